// Round 5
// baseline (567.965 us; speedup 1.0000x reference)
//
#include <hip/hip_runtime.h>

typedef float f4 __attribute__((ext_vector_type(4)));
typedef float f2 __attribute__((ext_vector_type(2)));

#define B_ 32
#define D_ 128
#define T_ 1024
#define K_ 4096
#define NROWS (B_ * T_)   // 32768
#define BM 32             // rows per workgroup -> grid 1024 = 4 blocks/CU
#define LPX 134           // xs row stride: %8==0 bytes for b64, 2-way bank alias only

// numpy computes t = a*a elementwise, THEN pairwise-sums (no fma fusion).
__device__ __forceinline__ float opaquef(float x) { asm volatile("" : "+v"(x)); return x; }

// numpy pairwise_sum base case for n=128: 8 accumulators,
// ((r0+r1)+(r2+r3))+((r4+r5)+(r6+r7)). Bit-exact replica.
__device__ float np_sumsq128(const float* a) {
  float r[8];
#pragma unroll
  for (int j = 0; j < 8; ++j) r[j] = opaquef(a[j] * a[j]);
#pragma unroll
  for (int i = 8; i < 128; i += 8) {
#pragma unroll
    for (int j = 0; j < 8; ++j) r[j] = r[j] + opaquef(a[i + j] * a[i + j]);
  }
  return ((r[0] + r[1]) + (r[2] + r[3])) + ((r[4] + r[5]) + (r[6] + r[7]));
}

__global__ void wsq_kernel(const float* __restrict__ W, float* __restrict__ wsq) {
  int k = blockIdx.x * blockDim.x + threadIdx.x;
  if (k < K_) wsq[k] = np_sumsq128(W + (size_t)k * D_);
}

// Wtb[(k>>8)][d][k&255] = W[k][d]  — K-blocked transpose, coalesced both sides.
__global__ void transpose_kernel(const float* __restrict__ W, float* __restrict__ Wtb) {
  __shared__ float t[32][33];
  int k0 = blockIdx.x * 32, d0 = blockIdx.y * 32;
  int lx = threadIdx.x & 31, ly = threadIdx.x >> 5;  // 256 thr: ly 0..7
  for (int i = ly; i < 32; i += 8) t[i][lx] = W[(size_t)(k0 + i) * D_ + d0 + lx];
  __syncthreads();
  size_t base = (size_t)(k0 >> 8) * (D_ * 256) + (k0 & 255);
  for (int i = ly; i < 32; i += 8) Wtb[base + (size_t)(d0 + i) * 256 + lx] = t[lx][i];
}

#define FMA_STEP(W0, W1, W2, W3, DOFF)                                   \
  do {                                                                   \
    f2 xu[4];                                                            \
    _Pragma("unroll")                                                    \
    for (int i = 0; i < 4; ++i) xu[i] = *(const f2*)(xrow[i] + (DOFF));  \
    _Pragma("unroll")                                                    \
    for (int i = 0; i < 4; ++i) {                                        \
      _Pragma("unroll")                                                  \
      for (int j = 0; j < 4; ++j) {                                      \
        float s_ = acc[i][j];                                            \
        s_ = __fmaf_rn(xu[i].x, W0[j], s_);   /* d   */                  \
        s_ = __fmaf_rn(xu[i].y, W2[j], s_);   /* d+1 */                  \
        acc[i][j] = s_;                                                  \
      }                                                                  \
      _Pragma("unroll")                                                  \
      for (int j = 0; j < 4; ++j) {                                      \
        float s_ = acc[i][j + 4];                                        \
        s_ = __fmaf_rn(xu[i].x, W1[j], s_);                              \
        s_ = __fmaf_rn(xu[i].y, W3[j], s_);                              \
        acc[i][j + 4] = s_;                                              \
      }                                                                  \
    }                                                                    \
  } while (0)

__global__ __launch_bounds__(256, 4) void argmin_kernel(
    const float* __restrict__ x, const float* __restrict__ Wtb,
    const float* __restrict__ wsq, int* __restrict__ qout,
    float* __restrict__ out2) {
  __shared__ float xs[BM][LPX];
  __shared__ float xsqs[BM];
  const int tid = threadIdx.x;
  const int blk = blockIdx.x;
  const int b  = blk >> 5;            // / (T_/BM)
  const int t0 = (blk & 31) * BM;
  const int tx = tid & 31;            // 8 consecutive codes: tx*8..tx*8+7 per 256-tile
  const int ty = tid >> 5;            // rows ty*4..ty*4+3

  // stage x tile: xs[tt][d] = x[b, d, t0+tt]   (coalesced along t)
  {
    int tt = tid & 31;
    int d0 = (tid >> 5) * 16;
    for (int dd = 0; dd < 16; ++dd) {
      int d = d0 + dd;
      xs[tt][d] = x[((size_t)b * D_ + d) * T_ + t0 + tt];
    }
  }
  __syncthreads();
  if (tid < BM) xsqs[tid] = np_sumsq128(&xs[tid][0]);
  __syncthreads();

  float xq[4];
#pragma unroll
  for (int i = 0; i < 4; ++i) xq[i] = xsqs[ty * 4 + i];
  const float* xrow[4];
#pragma unroll
  for (int i = 0; i < 4; ++i) xrow[i] = &xs[ty * 4 + i][0];

  float m1[4];
  int   i1[4];
#pragma unroll
  for (int i = 0; i < 4; ++i) { m1[i] = 3.4e38f; i1[i] = 0x7fffffff; }

  for (int kt = 0; kt < K_ / 256; ++kt) {
    const float* pw = Wtb + (size_t)kt * (D_ * 256) + tx * 8;

    float acc[4][8];
#pragma unroll
    for (int i = 0; i < 4; ++i)
#pragma unroll
      for (int j = 0; j < 8; ++j) acc[i][j] = 0.f;

    // ping-pong W buffers, d2 granularity: u = (d,d+1), v = (d+2,d+3)
    f4 u0 = *(const f4*)(pw + 0),   u1 = *(const f4*)(pw + 4);
    f4 u2 = *(const f4*)(pw + 256), u3 = *(const f4*)(pw + 260);
    f4 v0, v1, v2, v3;

    for (int s = 0; s < 32; ++s) {
      const int d = s * 4;
      v0 = *(const f4*)(pw + (d + 2) * 256);
      v1 = *(const f4*)(pw + (d + 2) * 256 + 4);
      v2 = *(const f4*)(pw + (d + 3) * 256);
      v3 = *(const f4*)(pw + (d + 3) * 256 + 4);
      FMA_STEP(u0, u1, u2, u3, d);          // ascending-d fma chain preserved
      u0 = *(const f4*)(pw + (d + 4) * 256);          // s=31: overread into slack
      u1 = *(const f4*)(pw + (d + 4) * 256 + 4);
      u2 = *(const f4*)(pw + (d + 5) * 256);
      u3 = *(const f4*)(pw + (d + 5) * 256 + 4);
      FMA_STEP(v0, v1, v2, v3, d + 2);
    }

    // epilogue: ascending k within thread (j ascending)
    const int kb = kt * 256 + tx * 8;
    f4 wqa = *(const f4*)&wsq[kb];
    f4 wqb = *(const f4*)&wsq[kb + 4];
#pragma unroll
    for (int j = 0; j < 4; ++j) {
#pragma unroll
      for (int i = 0; i < 4; ++i) {
        float t = __fmaf_rn(-2.0f, acc[i][j], wqa[j]);  // RN(wq - 2*mm)
        float v = __fadd_rn(t, xq[i]);                   // quantizing add
        if (v < m1[i]) { m1[i] = v; i1[i] = kb + j; }    // strict < => first occurrence
      }
    }
#pragma unroll
    for (int j = 0; j < 4; ++j) {
#pragma unroll
      for (int i = 0; i < 4; ++i) {
        float t = __fmaf_rn(-2.0f, acc[i][j + 4], wqb[j]);
        float v = __fadd_rn(t, xq[i]);
        if (v < m1[i]) { m1[i] = v; i1[i] = kb + 4 + j; }
      }
    }
  }

  // cross-lane reduce over tx (32 lanes, stays within half-wave), index tie-break
#pragma unroll
  for (int i = 0; i < 4; ++i) {
    float m = m1[i];
    int   idx = i1[i];
#pragma unroll
    for (int mask = 16; mask >= 1; mask >>= 1) {
      float mo = __shfl_xor(m, mask);
      int   io = __shfl_xor(idx, mask);
      if (mo < m || (mo == m && io < idx)) { m = mo; idx = io; }
    }
    if (tx == 0) {
      int rg = b * T_ + t0 + ty * 4 + i;
      qout[rg] = idx;
      out2[rg] = (float)idx;
    }
  }
}

// out0[r, d] = W[q[r], d]  — coalesced along d
__global__ void scatter0_kernel(const float* __restrict__ W,
                                const int* __restrict__ q,
                                float* __restrict__ out0) {
  int r = blockIdx.x * 2 + (threadIdx.x >> 7);
  int d = threadIdx.x & 127;
  out0[(size_t)r * D_ + d] = W[(size_t)q[r] * D_ + d];
}

// out1[b, d, t] = W[q[b,t], d]  — coalesced along t
__global__ void scatter1_kernel(const float* __restrict__ W,
                                const int* __restrict__ q,
                                float* __restrict__ out1) {
  int b = blockIdx.x >> 7;
  int d = blockIdx.x & 127;
  for (int t = threadIdx.x; t < T_; t += 256) {
    int k = q[b * T_ + t];
    out1[((size_t)b * D_ + d) * T_ + t] = W[(size_t)k * D_ + d];
  }
}

extern "C" void kernel_launch(void* const* d_in, const int* in_sizes, int n_in,
                              void* d_out, int out_size, void* d_ws, size_t ws_size,
                              hipStream_t stream) {
  const float* x = (const float*)d_in[0];
  const float* W = (const float*)d_in[1];
  float* out  = (float*)d_out;
  float* out0 = out;                           // [B,T,D]  4194304
  float* out1 = out + (size_t)NROWS * D_;      // [B,D,T]  4194304
  float* out2 = out + 2 * (size_t)NROWS * D_;  // [B,T]    32768 (as float)

  float* wsq = (float*)d_ws;                              // 16 KB
  int*   q   = (int*)((char*)d_ws + K_ * sizeof(float));  // 128 KB
  size_t base = K_ * sizeof(float) + NROWS * sizeof(int);
  // Wtb (2 MB + 8 KB prefetch slack): workspace if it fits, else stash in out0
  // (argmin reads it, scatter0 overwrites it afterwards — stream-ordered).
  float* Wtb = (ws_size >= base + (size_t)K_ * D_ * sizeof(float) + 8192)
                   ? (float*)((char*)d_ws + base)
                   : out0;

  wsq_kernel<<<K_ / 256, 256, 0, stream>>>(W, wsq);
  {
    dim3 g(K_ / 32, D_ / 32);
    transpose_kernel<<<g, 256, 0, stream>>>(W, Wtb);
  }
  argmin_kernel<<<NROWS / BM, 256, 0, stream>>>(x, Wtb, wsq, q, out2);
  scatter0_kernel<<<NROWS / 2, 256, 0, stream>>>(W, q, out0);
  scatter1_kernel<<<B_ * D_, 256, 0, stream>>>(W, q, out1);
}